// Round 4
// baseline (3856.844 us; speedup 1.0000x reference)
//
#include <hip/hip_runtime.h>
#include <hip/hip_bf16.h>
#include <math.h>

#define V_NODES 50000
#define E_EDGES 25000
#define NNZ     600000
#define S_SUB   8
#define K_SUB   16
#define DD      128      // S*K
#define NUM_STEP 4
#define EPSF    1e-10f

// stats layout per side (side = 2*step + {0:Y,1:X}), stride 2177 floats:
// [0] entropy sum; [1..128] colsum; [129..2176] gram (s*256 + i*16 + j)
#define STATS_STRIDE 2177

// ---------------- softmax over groups of 16 (gumbel-softmax X0) -------------
__global__ void softmax16_kernel(const float* __restrict__ emb,
                                 const float* __restrict__ gum,
                                 float* __restrict__ X) {
    int i = blockIdx.x * blockDim.x + threadIdx.x;
    if (i >= V_NODES * DD) return;
    float x = emb[i] + gum[i];          // TAU = 1.0
    float m = x;
    #pragma unroll
    for (int off = 1; off < 16; off <<= 1) m = fmaxf(m, __shfl_xor(m, off, 16));
    float e = expf(x - m);
    float s = e;
    #pragma unroll
    for (int off = 1; off < 16; off <<= 1) s += __shfl_xor(s, off, 16);
    X[i] = e / s;
}

// ---------------- int histogram of segment counts ---------------------------
__global__ void hist_kernel(const int* __restrict__ Vi, const int* __restrict__ Ei,
                            int* __restrict__ cntV, int* __restrict__ cntE) {
    int n = blockIdx.x * blockDim.x + threadIdx.x;
    if (n >= NNZ) return;
    atomicAdd(&cntV[Vi[n]], 1);
    atomicAdd(&cntE[Ei[n]], 1);
}

// ------------- exclusive scans for both segment arrays (2 blocks) -----------
__global__ void scan2_kernel(const int* __restrict__ cntE, const int* __restrict__ cntV,
                             int* __restrict__ offE, int* __restrict__ offV,
                             int* __restrict__ curE, int* __restrict__ curV) {
    const int  N   = (blockIdx.x == 0) ? E_EDGES : V_NODES;
    const int* cnt = (blockIdx.x == 0) ? cntE : cntV;
    int* off       = (blockIdx.x == 0) ? offE : offV;
    int* cur       = (blockIdx.x == 0) ? curE : curV;

    __shared__ int tmp[1024];
    __shared__ int sh_carry;
    int t = threadIdx.x;
    if (t == 0) sh_carry = 0;
    __syncthreads();
    for (int base = 0; base < N; base += 1024) {
        int c = sh_carry;
        int i = base + t;
        int v = (i < N) ? cnt[i] : 0;
        tmp[t] = v; __syncthreads();
        for (int st = 1; st < 1024; st <<= 1) {
            int add = (t >= st) ? tmp[t - st] : 0;
            __syncthreads();
            tmp[t] += add;
            __syncthreads();
        }
        if (i < N) { int e = c + tmp[t] - v; off[i] = e; cur[i] = e; }
        __syncthreads();
        if (t == 1023) sh_carry = c + tmp[1023];
        __syncthreads();
    }
}

// ---------------- fill CSR adjacency lists ----------------------------------
__global__ void fill_kernel(const int* __restrict__ Vi, const int* __restrict__ Ei,
                            int* __restrict__ curE, int* __restrict__ curV,
                            int* __restrict__ listE, int* __restrict__ listV) {
    int n = blockIdx.x * blockDim.x + threadIdx.x;
    if (n >= NNZ) return;
    int v = Vi[n], e = Ei[n];
    listE[atomicAdd(&curE[e], 1)] = v;
    listV[atomicAdd(&curV[v], 1)] = e;
}

// ---------------- segmented mean: one wave per destination row --------------
__global__ void gather_mean(const float* __restrict__ src,
                            float* __restrict__ dst,
                            const int* __restrict__ list,
                            const int* __restrict__ off,
                            const int* __restrict__ cnt,
                            int N) {
    int wid = (blockIdx.x * blockDim.x + threadIdx.x) >> 6;
    if (wid >= N) return;
    int lane = threadIdx.x & 63;
    int o   = off[wid];
    int deg = cnt[wid];
    const float2* s2 = (const float2*)src;

    float2 a0{0.f,0.f}, a1{0.f,0.f}, a2{0.f,0.f}, a3{0.f,0.f};
    int k = 0;
    for (; k + 4 <= deg; k += 4) {
        int i0 = list[o+k];
        int i1 = list[o+k+1];
        int i2 = list[o+k+2];
        int i3 = list[o+k+3];
        float2 v0 = s2[(size_t)i0*64 + lane];
        float2 v1 = s2[(size_t)i1*64 + lane];
        float2 v2 = s2[(size_t)i2*64 + lane];
        float2 v3 = s2[(size_t)i3*64 + lane];
        a0.x += v0.x; a0.y += v0.y;
        a1.x += v1.x; a1.y += v1.y;
        a2.x += v2.x; a2.y += v2.y;
        a3.x += v3.x; a3.y += v3.y;
    }
    for (; k < deg; ++k) {
        int i0 = list[o+k];
        float2 v0 = s2[(size_t)i0*64 + lane];
        a0.x += v0.x; a0.y += v0.y;
    }
    float inv = 1.0f / fmaxf((float)deg, 1.0f);
    float2 r;
    r.x = (a0.x + a1.x + a2.x + a3.x) * inv;
    r.y = (a0.y + a1.y + a2.y + a3.y) * inv;
    ((float2*)dst)[(size_t)wid*64 + lane] = r;
}

// -------- read-only stats pass: entropy / colsum / gram over M --------------
__global__ void stats_kernel(const float* __restrict__ M, int N,
                             float* __restrict__ stats) {
    int t = threadIdx.x;
    int r0 = t >> 7;         // row-in-pair (0/1)
    int d = t & 127;         // column
    int s = d >> 4;          // subspace
    int i = d & 15;          // index within subspace

    float ent = 0.f, col = 0.f;
    float gram[16];
    #pragma unroll
    for (int j = 0; j < 16; ++j) gram[j] = 0.f;

    for (int row = blockIdx.x * 2 + r0; row < N; row += gridDim.x * 2) {
        float y = M[(size_t)row * DD + d];
        ent -= y * logf(y + EPSF);
        col += y;
        #pragma unroll
        for (int j = 0; j < 16; ++j) {
            float yj = __shfl(y, j, 16);   // broadcast within 16-lane group
            gram[j] += y * yj;
        }
    }

    __shared__ float red[256];
    red[t] = ent; __syncthreads();
    for (int st = 128; st > 0; st >>= 1) {
        if (t < st) red[t] += red[t + st];
        __syncthreads();
    }
    if (t == 0) atomicAdd(&stats[0], red[0]);
    __syncthreads();
    red[t] = col; __syncthreads();
    if (t < 128) atomicAdd(&stats[1 + d], red[t] + red[t + 128]);
    __syncthreads();
    for (int j = 0; j < 16; ++j) {
        red[t] = gram[j]; __syncthreads();
        if (t < 128) atomicAdd(&stats[129 + s * 256 + i * 16 + j], red[t] + red[t + 128]);
        __syncthreads();
    }
}

// ---------------- final loss from the 8 stats blocks ------------------------
__global__ void loss_kernel(const float* __restrict__ stats, float* __restrict__ out) {
    int t = threadIdx.x;
    float acc_l = 0.f, acc_g = 0.f;

    if (t < 8) {
        float N = (t & 1) ? (float)V_NODES : (float)E_EDGES;
        acc_l = stats[t * STATS_STRIDE] / (N * (float)S_SUB);
    }

    for (int u = t; u < 8 * 128; u += blockDim.x) {
        int side = u >> 7, d = u & 127;
        float N = (side & 1) ? (float)V_NODES : (float)E_EDGES;
        float p = stats[side * STATS_STRIDE + 1 + d] / N;
        acc_g += p * logf(p + EPSF) / (float)S_SUB;
    }

    for (int u = t; u < 8 * 8 * 16; u += blockDim.x) {
        int side = u >> 7;
        int s = (u >> 4) & 7;
        int i = u & 15;
        const float* G = stats + side * STATS_STRIDE + 129 + s * 256;
        float nii = sqrtf(G[i * 16 + i]);
        float C[16];
        float m = -INFINITY;
        #pragma unroll
        for (int j = 0; j < 16; ++j) {
            float njj = sqrtf(G[j * 16 + j]);
            float c = G[i * 16 + j] / fmaxf(nii * njj, EPSF);
            C[j] = c;
            m = fmaxf(m, c);
        }
        float sum = 0.f;
        #pragma unroll
        for (int j = 0; j < 16; ++j) sum += expf(C[j] - m);
        float lse = logf(sum) + m;
        acc_g += (lse - C[i]) / (float)(S_SUB * K_SUB);
    }

    __shared__ float redl[256], redg[256];
    redl[t] = acc_l; redg[t] = acc_g; __syncthreads();
    for (int st = 128; st > 0; st >>= 1) {
        if (t < st) { redl[t] += redl[t + st]; redg[t] += redg[t + st]; }
        __syncthreads();
    }
    if (t == 0) { out[0] = redl[0]; out[1] = redg[0]; }
}

extern "C" void kernel_launch(void* const* d_in, const int* in_sizes, int n_in,
                              void* d_out, int out_size, void* d_ws, size_t ws_size,
                              hipStream_t stream) {
    const float* emb = (const float*)d_in[0];
    const float* gum = (const float*)d_in[1];
    const int*   Vi  = (const int*)d_in[2];
    const int*   Ei  = (const int*)d_in[3];
    float* out = (float*)d_out;

    char* ws = (char*)d_ws;
    size_t off = 0;
    float* X = (float*)(ws + off);      off += (size_t)V_NODES * DD * 4;   // 25.6 MB
    float* Y = (float*)(ws + off);      off += (size_t)E_EDGES * DD * 4;   // 12.8 MB
    int* listE = (int*)(ws + off);      off += (size_t)NNZ * 4;            // 2.4 MB
    int* listV = (int*)(ws + off);      off += (size_t)NNZ * 4;            // 2.4 MB
    int* cntE  = (int*)(ws + off);      off += (size_t)E_EDGES * 4;
    int* cntV  = (int*)(ws + off);      off += (size_t)V_NODES * 4;
    int* offE  = (int*)(ws + off);      off += (size_t)E_EDGES * 4;
    int* offV  = (int*)(ws + off);      off += (size_t)V_NODES * 4;
    int* curE  = (int*)(ws + off);      off += (size_t)E_EDGES * 4;
    int* curV  = (int*)(ws + off);      off += (size_t)V_NODES * 4;
    float* stats = (float*)(ws + off);  off += (size_t)8 * STATS_STRIDE * 4;

    // zero counts + stats every launch (deterministic state)
    hipMemsetAsync(cntE, 0, ((size_t)E_EDGES + V_NODES) * 4, stream);
    hipMemsetAsync(stats, 0, (size_t)8 * STATS_STRIDE * 4, stream);

    softmax16_kernel<<<(V_NODES * DD + 255) / 256, 256, 0, stream>>>(emb, gum, X);
    hist_kernel<<<(NNZ + 255) / 256, 256, 0, stream>>>(Vi, Ei, cntV, cntE);
    scan2_kernel<<<2, 1024, 0, stream>>>(cntE, cntV, offE, offV, curE, curV);
    fill_kernel<<<(NNZ + 255) / 256, 256, 0, stream>>>(Vi, Ei, curE, curV, listE, listV);

    const int SB = 1024;   // stats grid: 4 blocks/CU -> 16 waves/CU
    for (int step = 0; step < NUM_STEP; ++step) {
        // Y = scatter_mean(X[Vi], Ei): one wave per edge row
        gather_mean<<<(E_EDGES * 64 + 255) / 256, 256, 0, stream>>>(X, Y, listE, offE, cntE, E_EDGES);
        stats_kernel<<<SB, 256, 0, stream>>>(Y, E_EDGES, stats + (2 * step) * STATS_STRIDE);
        // X = scatter_mean(Y[Ei], Vi): one wave per node row
        gather_mean<<<(V_NODES * 64 + 255) / 256, 256, 0, stream>>>(Y, X, listV, offV, cntV, V_NODES);
        stats_kernel<<<SB, 256, 0, stream>>>(X, V_NODES, stats + (2 * step + 1) * STATS_STRIDE);
    }

    loss_kernel<<<1, 256, 0, stream>>>(stats, out);
}

// Round 5
// 816.825 us; speedup vs baseline: 4.7218x; 4.7218x over previous
//
#include <hip/hip_runtime.h>
#include <hip/hip_bf16.h>
#include <math.h>

#define V_NODES 50000
#define E_EDGES 25000
#define NNZ     600000
#define S_SUB   8
#define K_SUB   16
#define DD      128      // S*K
#define NUM_STEP 4
#define EPSF    1e-10f

// stats layout per side (side = 2*step + {0:Y,1:X}), stride 2177 floats:
// [0] entropy sum; [1..128] colsum; [129..2176] gram (s*256 + i*16 + j)
#define STATS_STRIDE 2177
#define NB_STATS 256     // stage-1 partial blocks

// ---------------- softmax over groups of 16 (gumbel-softmax X0) -------------
__global__ void softmax16_kernel(const float* __restrict__ emb,
                                 const float* __restrict__ gum,
                                 float* __restrict__ X) {
    int i = blockIdx.x * blockDim.x + threadIdx.x;
    if (i >= V_NODES * DD) return;
    float x = emb[i] + gum[i];          // TAU = 1.0
    float m = x;
    #pragma unroll
    for (int off = 1; off < 16; off <<= 1) m = fmaxf(m, __shfl_xor(m, off, 16));
    float e = expf(x - m);
    float s = e;
    #pragma unroll
    for (int off = 1; off < 16; off <<= 1) s += __shfl_xor(s, off, 16);
    X[i] = e / s;
}

// ---------------- int histogram of segment counts ---------------------------
__global__ void hist_kernel(const int* __restrict__ Vi, const int* __restrict__ Ei,
                            int* __restrict__ cntV, int* __restrict__ cntE) {
    int n = blockIdx.x * blockDim.x + threadIdx.x;
    if (n >= NNZ) return;
    atomicAdd(&cntV[Vi[n]], 1);
    atomicAdd(&cntE[Ei[n]], 1);
}

// ------------- exclusive scans (wave-shfl based, 2 blocks) ------------------
__global__ void scan2_kernel(const int* __restrict__ cntE, const int* __restrict__ cntV,
                             int* __restrict__ offE, int* __restrict__ offV,
                             int* __restrict__ curE, int* __restrict__ curV) {
    const int  N   = (blockIdx.x == 0) ? E_EDGES : V_NODES;
    const int* cnt = (blockIdx.x == 0) ? cntE : cntV;
    int* off       = (blockIdx.x == 0) ? offE : offV;
    int* cur       = (blockIdx.x == 0) ? curE : curV;

    __shared__ int wsum[16];
    __shared__ int sh_carry;
    int t = threadIdx.x, lane = t & 63, w = t >> 6;
    if (t == 0) sh_carry = 0;
    __syncthreads();
    for (int base = 0; base < N; base += 1024) {
        int i = base + t;
        int v = (i < N) ? cnt[i] : 0;
        int x = v;
        #pragma unroll
        for (int d = 1; d < 64; d <<= 1) {
            int u = __shfl_up(x, d, 64);
            if (lane >= d) x += u;
        }
        if (lane == 63) wsum[w] = x;
        __syncthreads();
        int c = sh_carry;
        __syncthreads();
        if (t == 0) {
            int acc = 0;
            #pragma unroll
            for (int k = 0; k < 16; ++k) { int tk = wsum[k]; wsum[k] = acc; acc += tk; }
            sh_carry = c + acc;
        }
        __syncthreads();
        if (i < N) {
            int e = c + wsum[w] + (x - v);   // exclusive prefix
            off[i] = e; cur[i] = e;
        }
        __syncthreads();
    }
}

// ---------------- fill CSR adjacency lists ----------------------------------
__global__ void fill_kernel(const int* __restrict__ Vi, const int* __restrict__ Ei,
                            int* __restrict__ curE, int* __restrict__ curV,
                            int* __restrict__ listE, int* __restrict__ listV) {
    int n = blockIdx.x * blockDim.x + threadIdx.x;
    if (n >= NNZ) return;
    int v = Vi[n], e = Ei[n];
    listE[atomicAdd(&curE[e], 1)] = v;
    listV[atomicAdd(&curV[v], 1)] = e;
}

// ---------------- segmented mean: one wave per destination row --------------
__global__ void gather_mean(const float* __restrict__ src,
                            float* __restrict__ dst,
                            const int* __restrict__ list,
                            const int* __restrict__ off,
                            const int* __restrict__ cnt,
                            int N) {
    int wid = (blockIdx.x * blockDim.x + threadIdx.x) >> 6;
    if (wid >= N) return;
    int lane = threadIdx.x & 63;
    int o   = off[wid];
    int deg = cnt[wid];
    const float2* s2 = (const float2*)src;

    float2 a0{0.f,0.f}, a1{0.f,0.f}, a2{0.f,0.f}, a3{0.f,0.f};
    int k = 0;
    for (; k + 4 <= deg; k += 4) {
        int i0 = list[o+k];
        int i1 = list[o+k+1];
        int i2 = list[o+k+2];
        int i3 = list[o+k+3];
        float2 v0 = s2[(size_t)i0*64 + lane];
        float2 v1 = s2[(size_t)i1*64 + lane];
        float2 v2 = s2[(size_t)i2*64 + lane];
        float2 v3 = s2[(size_t)i3*64 + lane];
        a0.x += v0.x; a0.y += v0.y;
        a1.x += v1.x; a1.y += v1.y;
        a2.x += v2.x; a2.y += v2.y;
        a3.x += v3.x; a3.y += v3.y;
    }
    for (; k < deg; ++k) {
        int i0 = list[o+k];
        float2 v0 = s2[(size_t)i0*64 + lane];
        a0.x += v0.x; a0.y += v0.y;
    }
    float inv = 1.0f / fmaxf((float)deg, 1.0f);
    float2 r;
    r.x = (a0.x + a1.x + a2.x + a3.x) * inv;
    r.y = (a0.y + a1.y + a2.y + a3.y) * inv;
    ((float2*)dst)[(size_t)wid*64 + lane] = r;
}

// -------- stats stage 1: per-block partials, NO atomics ---------------------
// 1024 threads: 8 row-slots x 128 columns; each thread does 2 rows per iter.
__global__ void stats1_kernel(const float* __restrict__ M, int N,
                              float* __restrict__ partials) {
    int t = threadIdx.x;
    int slot = t >> 7;       // 0..7
    int d = t & 127;         // column
    int s = d >> 4;          // subspace
    int i = d & 15;          // index within subspace

    float ent = 0.f, col = 0.f;
    float gram[16];
    #pragma unroll
    for (int j = 0; j < 16; ++j) gram[j] = 0.f;

    for (int row0 = blockIdx.x * 16 + slot * 2; row0 < N; row0 += NB_STATS * 16) {
        float ya = M[(size_t)row0 * DD + d];
        int row1 = row0 + 1;
        float yb = (row1 < N) ? M[(size_t)row1 * DD + d] : 0.f;
        ent -= ya * logf(ya + EPSF) + yb * logf(yb + EPSF);
        col += ya + yb;
        #pragma unroll
        for (int j = 0; j < 16; ++j) {
            gram[j] += ya * __shfl(ya, j, 16) + yb * __shfl(yb, j, 16);
        }
    }

    float* part = partials + (size_t)blockIdx.x * STATS_STRIDE;
    __shared__ float red[1024];
    // entropy: full block reduce
    red[t] = ent; __syncthreads();
    for (int st = 512; st > 0; st >>= 1) {
        if (t < st) red[t] += red[t + st];
        __syncthreads();
    }
    if (t == 0) part[0] = red[0];
    __syncthreads();
    // colsum: 8 slots share column d
    red[t] = col; __syncthreads();
    if (t < 128) {
        float v = red[t];
        #pragma unroll
        for (int k = 1; k < 8; ++k) v += red[t + 128 * k];
        part[1 + d] = v;
    }
    __syncthreads();
    // gram
    for (int j = 0; j < 16; ++j) {
        red[t] = gram[j]; __syncthreads();
        if (t < 128) {
            float v = red[t];
            #pragma unroll
            for (int k = 1; k < 8; ++k) v += red[t + 128 * k];
            part[129 + s * 256 + i * 16 + j] = v;
        }
        __syncthreads();
    }
}

// -------- stats stage 2: sum NB_STATS partials -> stats[side] ---------------
__global__ void reduce9_kernel(const float* __restrict__ partials,
                               float* __restrict__ stats_side) {
    int e = blockIdx.x * blockDim.x + threadIdx.x;
    if (e >= STATS_STRIDE) return;
    float acc = 0.f;
    #pragma unroll 8
    for (int b = 0; b < NB_STATS; ++b)
        acc += partials[(size_t)b * STATS_STRIDE + e];
    stats_side[e] = acc;
}

// ---------------- final loss from the 8 stats blocks ------------------------
__global__ void loss_kernel(const float* __restrict__ stats, float* __restrict__ out) {
    int t = threadIdx.x;
    float acc_l = 0.f, acc_g = 0.f;

    if (t < 8) {
        float N = (t & 1) ? (float)V_NODES : (float)E_EDGES;
        acc_l = stats[t * STATS_STRIDE] / (N * (float)S_SUB);
    }

    for (int u = t; u < 8 * 128; u += blockDim.x) {
        int side = u >> 7, d = u & 127;
        float N = (side & 1) ? (float)V_NODES : (float)E_EDGES;
        float p = stats[side * STATS_STRIDE + 1 + d] / N;
        acc_g += p * logf(p + EPSF) / (float)S_SUB;
    }

    for (int u = t; u < 8 * 8 * 16; u += blockDim.x) {
        int side = u >> 7;
        int s = (u >> 4) & 7;
        int i = u & 15;
        const float* G = stats + side * STATS_STRIDE + 129 + s * 256;
        float nii = sqrtf(G[i * 16 + i]);
        float C[16];
        float m = -INFINITY;
        #pragma unroll
        for (int j = 0; j < 16; ++j) {
            float njj = sqrtf(G[j * 16 + j]);
            float c = G[i * 16 + j] / fmaxf(nii * njj, EPSF);
            C[j] = c;
            m = fmaxf(m, c);
        }
        float sum = 0.f;
        #pragma unroll
        for (int j = 0; j < 16; ++j) sum += expf(C[j] - m);
        float lse = logf(sum) + m;
        acc_g += (lse - C[i]) / (float)(S_SUB * K_SUB);
    }

    __shared__ float redl[256], redg[256];
    redl[t] = acc_l; redg[t] = acc_g; __syncthreads();
    for (int st = 128; st > 0; st >>= 1) {
        if (t < st) { redl[t] += redl[t + st]; redg[t] += redg[t + st]; }
        __syncthreads();
    }
    if (t == 0) { out[0] = redl[0]; out[1] = redg[0]; }
}

extern "C" void kernel_launch(void* const* d_in, const int* in_sizes, int n_in,
                              void* d_out, int out_size, void* d_ws, size_t ws_size,
                              hipStream_t stream) {
    const float* emb = (const float*)d_in[0];
    const float* gum = (const float*)d_in[1];
    const int*   Vi  = (const int*)d_in[2];
    const int*   Ei  = (const int*)d_in[3];
    float* out = (float*)d_out;

    char* ws = (char*)d_ws;
    size_t off = 0;
    float* X = (float*)(ws + off);      off += (size_t)V_NODES * DD * 4;   // 25.6 MB
    float* Y = (float*)(ws + off);      off += (size_t)E_EDGES * DD * 4;   // 12.8 MB
    int* listE = (int*)(ws + off);      off += (size_t)NNZ * 4;            // 2.4 MB
    int* listV = (int*)(ws + off);      off += (size_t)NNZ * 4;            // 2.4 MB
    int* cntE  = (int*)(ws + off);      off += (size_t)E_EDGES * 4;
    int* cntV  = (int*)(ws + off);      off += (size_t)V_NODES * 4;
    int* offE  = (int*)(ws + off);      off += (size_t)E_EDGES * 4;
    int* offV  = (int*)(ws + off);      off += (size_t)V_NODES * 4;
    int* curE  = (int*)(ws + off);      off += (size_t)E_EDGES * 4;
    int* curV  = (int*)(ws + off);      off += (size_t)V_NODES * 4;
    float* stats = (float*)(ws + off);  off += (size_t)8 * STATS_STRIDE * 4;
    float* partials = (float*)(ws + off); off += (size_t)NB_STATS * STATS_STRIDE * 4; // 2.2 MB

    // zero counts (hist accumulates); stats/partials fully overwritten each call
    hipMemsetAsync(cntE, 0, ((size_t)E_EDGES + V_NODES) * 4, stream);

    softmax16_kernel<<<(V_NODES * DD + 255) / 256, 256, 0, stream>>>(emb, gum, X);
    hist_kernel<<<(NNZ + 255) / 256, 256, 0, stream>>>(Vi, Ei, cntV, cntE);
    scan2_kernel<<<2, 1024, 0, stream>>>(cntE, cntV, offE, offV, curE, curV);
    fill_kernel<<<(NNZ + 255) / 256, 256, 0, stream>>>(Vi, Ei, curE, curV, listE, listV);

    const int RB = (STATS_STRIDE + 255) / 256;   // 9 blocks
    for (int step = 0; step < NUM_STEP; ++step) {
        // Y = scatter_mean(X[Vi], Ei): one wave per edge row
        gather_mean<<<(E_EDGES * 64 + 255) / 256, 256, 0, stream>>>(X, Y, listE, offE, cntE, E_EDGES);
        stats1_kernel<<<NB_STATS, 1024, 0, stream>>>(Y, E_EDGES, partials);
        reduce9_kernel<<<RB, 256, 0, stream>>>(partials, stats + (2 * step) * STATS_STRIDE);
        // X = scatter_mean(Y[Ei], Vi): one wave per node row
        gather_mean<<<(V_NODES * 64 + 255) / 256, 256, 0, stream>>>(Y, X, listV, offV, cntV, V_NODES);
        stats1_kernel<<<NB_STATS, 1024, 0, stream>>>(X, V_NODES, partials);
        reduce9_kernel<<<RB, 256, 0, stream>>>(partials, stats + (2 * step + 1) * STATS_STRIDE);
    }

    loss_kernel<<<1, 256, 0, stream>>>(stats, out);
}

// Round 6
// 708.977 us; speedup vs baseline: 5.4400x; 1.1521x over previous
//
#include <hip/hip_runtime.h>
#include <hip/hip_bf16.h>
#include <hip/hip_fp16.h>
#include <math.h>

#define V_NODES 50000
#define E_EDGES 25000
#define NNZ     600000
#define S_SUB   8
#define K_SUB   16
#define DD      128      // S*K
#define NUM_STEP 4
#define EPSF    1e-10f

// stats layout per side (side = 2*step + {0:Y,1:X}), stride 2177 floats:
// [0] entropy sum; [1..128] colsum; [129..2176] gram (s*256 + i*16 + j)
#define STATS_STRIDE 2177
#define NB_STATS 256     // stage-1 partial blocks

// ------- softmax over groups of 16 cols (gumbel-softmax X0), fp16 out -------
// thread owns a column PAIR; subspace = 8 consecutive pair-lanes.
__global__ void softmax16_kernel(const float* __restrict__ emb,
                                 const float* __restrict__ gum,
                                 __half* __restrict__ X) {
    int i2 = blockIdx.x * blockDim.x + threadIdx.x;   // pair index
    if (i2 >= V_NODES * 64) return;
    const float2* e2 = (const float2*)emb;
    const float2* g2 = (const float2*)gum;
    float2 e = e2[i2], g = g2[i2];
    float xa = e.x + g.x, xb = e.y + g.y;   // TAU = 1.0
    float m = fmaxf(xa, xb);
    #pragma unroll
    for (int off = 1; off < 8; off <<= 1) m = fmaxf(m, __shfl_xor(m, off, 8));
    float ea = expf(xa - m), eb = expf(xb - m);
    float s = ea + eb;
    #pragma unroll
    for (int off = 1; off < 8; off <<= 1) s += __shfl_xor(s, off, 8);
    float inv = 1.0f / s;
    ((__half2*)X)[i2] = __floats2half2_rn(ea * inv, eb * inv);
}

// ---------------- int histogram of segment counts ---------------------------
__global__ void hist_kernel(const int* __restrict__ Vi, const int* __restrict__ Ei,
                            int* __restrict__ cntV, int* __restrict__ cntE) {
    int n = blockIdx.x * blockDim.x + threadIdx.x;
    if (n >= NNZ) return;
    atomicAdd(&cntV[Vi[n]], 1);
    atomicAdd(&cntE[Ei[n]], 1);
}

// ------------- exclusive scans (wave-shfl based, 2 blocks) ------------------
__global__ void scan2_kernel(const int* __restrict__ cntE, const int* __restrict__ cntV,
                             int* __restrict__ offE, int* __restrict__ offV,
                             int* __restrict__ curE, int* __restrict__ curV) {
    const int  N   = (blockIdx.x == 0) ? E_EDGES : V_NODES;
    const int* cnt = (blockIdx.x == 0) ? cntE : cntV;
    int* off       = (blockIdx.x == 0) ? offE : offV;
    int* cur       = (blockIdx.x == 0) ? curE : curV;

    __shared__ int wsum[16];
    __shared__ int sh_carry;
    int t = threadIdx.x, lane = t & 63, w = t >> 6;
    if (t == 0) sh_carry = 0;
    __syncthreads();
    for (int base = 0; base < N; base += 1024) {
        int i = base + t;
        int v = (i < N) ? cnt[i] : 0;
        int x = v;
        #pragma unroll
        for (int d = 1; d < 64; d <<= 1) {
            int u = __shfl_up(x, d, 64);
            if (lane >= d) x += u;
        }
        if (lane == 63) wsum[w] = x;
        __syncthreads();
        int c = sh_carry;
        __syncthreads();
        if (t == 0) {
            int acc = 0;
            #pragma unroll
            for (int k = 0; k < 16; ++k) { int tk = wsum[k]; wsum[k] = acc; acc += tk; }
            sh_carry = c + acc;
        }
        __syncthreads();
        if (i < N) {
            int e = c + wsum[w] + (x - v);   // exclusive prefix
            off[i] = e; cur[i] = e;
        }
        __syncthreads();
    }
}

// ---------------- fill CSR adjacency lists ----------------------------------
__global__ void fill_kernel(const int* __restrict__ Vi, const int* __restrict__ Ei,
                            int* __restrict__ curE, int* __restrict__ curV,
                            int* __restrict__ listE, int* __restrict__ listV) {
    int n = blockIdx.x * blockDim.x + threadIdx.x;
    if (n >= NNZ) return;
    int v = Vi[n], e = Ei[n];
    listE[atomicAdd(&curE[e], 1)] = v;
    listV[atomicAdd(&curV[v], 1)] = e;
}

// ------ segmented mean: one wave per destination row (fp16 src/dst) ---------
__global__ void gather_mean(const __half* __restrict__ src,
                            __half* __restrict__ dst,
                            const int* __restrict__ list,
                            const int* __restrict__ off,
                            const int* __restrict__ cnt,
                            int N) {
    int wid = (blockIdx.x * blockDim.x + threadIdx.x) >> 6;
    if (wid >= N) return;
    int lane = threadIdx.x & 63;
    int o   = off[wid];
    int deg = cnt[wid];
    const __half2* s2 = (const __half2*)src;

    float2 a0{0.f,0.f}, a1{0.f,0.f}, a2{0.f,0.f}, a3{0.f,0.f};
    int k = 0;
    for (; k + 4 <= deg; k += 4) {
        int i0 = list[o+k];
        int i1 = list[o+k+1];
        int i2 = list[o+k+2];
        int i3 = list[o+k+3];
        float2 v0 = __half22float2(s2[(size_t)i0*64 + lane]);
        float2 v1 = __half22float2(s2[(size_t)i1*64 + lane]);
        float2 v2 = __half22float2(s2[(size_t)i2*64 + lane]);
        float2 v3 = __half22float2(s2[(size_t)i3*64 + lane]);
        a0.x += v0.x; a0.y += v0.y;
        a1.x += v1.x; a1.y += v1.y;
        a2.x += v2.x; a2.y += v2.y;
        a3.x += v3.x; a3.y += v3.y;
    }
    for (; k < deg; ++k) {
        int i0 = list[o+k];
        float2 v0 = __half22float2(s2[(size_t)i0*64 + lane]);
        a0.x += v0.x; a0.y += v0.y;
    }
    float inv = 1.0f / fmaxf((float)deg, 1.0f);
    float2 r;
    r.x = (a0.x + a1.x + a2.x + a3.x) * inv;
    r.y = (a0.y + a1.y + a2.y + a3.y) * inv;
    ((__half2*)dst)[(size_t)wid*64 + lane] = __float22half2_rn(r);
}

// -------- stats stage 1: per-block partials, NO atomics (fp16 in) -----------
// 1024 threads: 8 row-slots x 128 columns; each thread does 2 rows per iter.
__global__ void stats1_kernel(const __half* __restrict__ M, int N,
                              float* __restrict__ partials) {
    int t = threadIdx.x;
    int slot = t >> 7;       // 0..7
    int d = t & 127;         // column
    int s = d >> 4;          // subspace
    int i = d & 15;          // index within subspace

    float ent = 0.f, col = 0.f;
    float gram[16];
    #pragma unroll
    for (int j = 0; j < 16; ++j) gram[j] = 0.f;

    for (int row0 = blockIdx.x * 16 + slot * 2; row0 < N; row0 += NB_STATS * 16) {
        float ya = __half2float(M[(size_t)row0 * DD + d]);
        int row1 = row0 + 1;
        float yb = (row1 < N) ? __half2float(M[(size_t)row1 * DD + d]) : 0.f;
        ent -= ya * logf(ya + EPSF) + yb * logf(yb + EPSF);
        col += ya + yb;
        #pragma unroll
        for (int j = 0; j < 16; ++j) {
            gram[j] += ya * __shfl(ya, j, 16) + yb * __shfl(yb, j, 16);
        }
    }

    float* part = partials + (size_t)blockIdx.x * STATS_STRIDE;
    __shared__ float red[1024];
    // entropy: full block reduce
    red[t] = ent; __syncthreads();
    for (int st = 512; st > 0; st >>= 1) {
        if (t < st) red[t] += red[t + st];
        __syncthreads();
    }
    if (t == 0) part[0] = red[0];
    __syncthreads();
    // colsum: 8 slots share column d
    red[t] = col; __syncthreads();
    if (t < 128) {
        float v = red[t];
        #pragma unroll
        for (int k = 1; k < 8; ++k) v += red[t + 128 * k];
        part[1 + d] = v;
    }
    __syncthreads();
    // gram
    for (int j = 0; j < 16; ++j) {
        red[t] = gram[j]; __syncthreads();
        if (t < 128) {
            float v = red[t];
            #pragma unroll
            for (int k = 1; k < 8; ++k) v += red[t + 128 * k];
            part[129 + s * 256 + i * 16 + j] = v;
        }
        __syncthreads();
    }
}

// -------- stats stage 2: sum NB_STATS partials -> stats[side] ---------------
__global__ void reduce9_kernel(const float* __restrict__ partials,
                               float* __restrict__ stats_side) {
    int e = blockIdx.x * blockDim.x + threadIdx.x;
    if (e >= STATS_STRIDE) return;
    float acc = 0.f;
    #pragma unroll 8
    for (int b = 0; b < NB_STATS; ++b)
        acc += partials[(size_t)b * STATS_STRIDE + e];
    stats_side[e] = acc;
}

// ---------------- final loss from the 8 stats blocks ------------------------
__global__ void loss_kernel(const float* __restrict__ stats, float* __restrict__ out) {
    int t = threadIdx.x;
    float acc_l = 0.f, acc_g = 0.f;

    if (t < 8) {
        float N = (t & 1) ? (float)V_NODES : (float)E_EDGES;
        acc_l = stats[t * STATS_STRIDE] / (N * (float)S_SUB);
    }

    for (int u = t; u < 8 * 128; u += blockDim.x) {
        int side = u >> 7, d = u & 127;
        float N = (side & 1) ? (float)V_NODES : (float)E_EDGES;
        float p = stats[side * STATS_STRIDE + 1 + d] / N;
        acc_g += p * logf(p + EPSF) / (float)S_SUB;
    }

    for (int u = t; u < 8 * 8 * 16; u += blockDim.x) {
        int side = u >> 7;
        int s = (u >> 4) & 7;
        int i = u & 15;
        const float* G = stats + side * STATS_STRIDE + 129 + s * 256;
        float nii = sqrtf(G[i * 16 + i]);
        float C[16];
        float m = -INFINITY;
        #pragma unroll
        for (int j = 0; j < 16; ++j) {
            float njj = sqrtf(G[j * 16 + j]);
            float c = G[i * 16 + j] / fmaxf(nii * njj, EPSF);
            C[j] = c;
            m = fmaxf(m, c);
        }
        float sum = 0.f;
        #pragma unroll
        for (int j = 0; j < 16; ++j) sum += expf(C[j] - m);
        float lse = logf(sum) + m;
        acc_g += (lse - C[i]) / (float)(S_SUB * K_SUB);
    }

    __shared__ float redl[256], redg[256];
    redl[t] = acc_l; redg[t] = acc_g; __syncthreads();
    for (int st = 128; st > 0; st >>= 1) {
        if (t < st) { redl[t] += redl[t + st]; redg[t] += redg[t + st]; }
        __syncthreads();
    }
    if (t == 0) { out[0] = redl[0]; out[1] = redg[0]; }
}

extern "C" void kernel_launch(void* const* d_in, const int* in_sizes, int n_in,
                              void* d_out, int out_size, void* d_ws, size_t ws_size,
                              hipStream_t stream) {
    const float* emb = (const float*)d_in[0];
    const float* gum = (const float*)d_in[1];
    const int*   Vi  = (const int*)d_in[2];
    const int*   Ei  = (const int*)d_in[3];
    float* out = (float*)d_out;

    char* ws = (char*)d_ws;
    size_t off = 0;
    __half* X = (__half*)(ws + off);    off += (size_t)V_NODES * DD * 2;   // 12.8 MB
    __half* Y = (__half*)(ws + off);    off += (size_t)E_EDGES * DD * 2;   // 6.4 MB
    int* listE = (int*)(ws + off);      off += (size_t)NNZ * 4;            // 2.4 MB
    int* listV = (int*)(ws + off);      off += (size_t)NNZ * 4;            // 2.4 MB
    int* cntE  = (int*)(ws + off);      off += (size_t)E_EDGES * 4;
    int* cntV  = (int*)(ws + off);      off += (size_t)V_NODES * 4;
    int* offE  = (int*)(ws + off);      off += (size_t)E_EDGES * 4;
    int* offV  = (int*)(ws + off);      off += (size_t)V_NODES * 4;
    int* curE  = (int*)(ws + off);      off += (size_t)E_EDGES * 4;
    int* curV  = (int*)(ws + off);      off += (size_t)V_NODES * 4;
    float* stats = (float*)(ws + off);  off += (size_t)8 * STATS_STRIDE * 4;
    float* partials = (float*)(ws + off); off += (size_t)NB_STATS * STATS_STRIDE * 4; // 2.2 MB

    // zero counts (hist accumulates); stats/partials fully overwritten each call
    hipMemsetAsync(cntE, 0, ((size_t)E_EDGES + V_NODES) * 4, stream);

    softmax16_kernel<<<(V_NODES * 64 + 255) / 256, 256, 0, stream>>>(emb, gum, X);
    hist_kernel<<<(NNZ + 255) / 256, 256, 0, stream>>>(Vi, Ei, cntV, cntE);
    scan2_kernel<<<2, 1024, 0, stream>>>(cntE, cntV, offE, offV, curE, curV);
    fill_kernel<<<(NNZ + 255) / 256, 256, 0, stream>>>(Vi, Ei, curE, curV, listE, listV);

    const int RB = (STATS_STRIDE + 255) / 256;   // 9 blocks
    for (int step = 0; step < NUM_STEP; ++step) {
        // Y = scatter_mean(X[Vi], Ei): one wave per edge row
        gather_mean<<<(E_EDGES * 64 + 255) / 256, 256, 0, stream>>>(X, Y, listE, offE, cntE, E_EDGES);
        stats1_kernel<<<NB_STATS, 1024, 0, stream>>>(Y, E_EDGES, partials);
        reduce9_kernel<<<RB, 256, 0, stream>>>(partials, stats + (2 * step) * STATS_STRIDE);
        // X = scatter_mean(Y[Ei], Vi): one wave per node row
        gather_mean<<<(V_NODES * 64 + 255) / 256, 256, 0, stream>>>(Y, X, listV, offV, cntV, V_NODES);
        stats1_kernel<<<NB_STATS, 1024, 0, stream>>>(X, V_NODES, partials);
        reduce9_kernel<<<RB, 256, 0, stream>>>(partials, stats + (2 * step + 1) * STATS_STRIDE);
    }

    loss_kernel<<<1, 256, 0, stream>>>(stats, out);
}

// Round 7
// 634.388 us; speedup vs baseline: 6.0796x; 1.1176x over previous
//
#include <hip/hip_runtime.h>
#include <hip/hip_bf16.h>
#include <hip/hip_fp16.h>
#include <math.h>

#define V_NODES 50000
#define E_EDGES 25000
#define NNZ     600000
#define S_SUB   8
#define K_SUB   16
#define DD      128      // S*K
#define NUM_STEP 4
#define EPSF    1e-10f

// stats layout per side (side = 2*step + {0:Y,1:X}), stride 2177 floats:
// [0] entropy sum; [1..128] colsum; [129..2176] gram (s*256 + i*16 + j)
#define STATS_STRIDE 2177
#define NBLK 256         // fused gather+stats grid (1 block/CU, 16 waves)

// ------- softmax over groups of 16 cols (gumbel-softmax X0), fp16 out -------
__global__ void softmax16_kernel(const float* __restrict__ emb,
                                 const float* __restrict__ gum,
                                 __half* __restrict__ X) {
    int i2 = blockIdx.x * blockDim.x + threadIdx.x;   // pair index
    if (i2 >= V_NODES * 64) return;
    const float2* e2 = (const float2*)emb;
    const float2* g2 = (const float2*)gum;
    float2 e = e2[i2], g = g2[i2];
    float xa = e.x + g.x, xb = e.y + g.y;   // TAU = 1.0
    float m = fmaxf(xa, xb);
    #pragma unroll
    for (int off = 1; off < 8; off <<= 1) m = fmaxf(m, __shfl_xor(m, off, 8));
    float ea = expf(xa - m), eb = expf(xb - m);
    float s = ea + eb;
    #pragma unroll
    for (int off = 1; off < 8; off <<= 1) s += __shfl_xor(s, off, 8);
    float inv = 1.0f / s;
    ((__half2*)X)[i2] = __floats2half2_rn(ea * inv, eb * inv);
}

// ---------------- int histogram of segment counts ---------------------------
__global__ void hist_kernel(const int* __restrict__ Vi, const int* __restrict__ Ei,
                            int* __restrict__ cntV, int* __restrict__ cntE) {
    int n = blockIdx.x * blockDim.x + threadIdx.x;
    if (n >= NNZ) return;
    atomicAdd(&cntV[Vi[n]], 1);
    atomicAdd(&cntE[Ei[n]], 1);
}

// ------------- exclusive scans (wave-shfl based, 2 blocks) ------------------
__global__ void scan2_kernel(const int* __restrict__ cntE, const int* __restrict__ cntV,
                             int* __restrict__ offE, int* __restrict__ offV,
                             int* __restrict__ curE, int* __restrict__ curV) {
    const int  N   = (blockIdx.x == 0) ? E_EDGES : V_NODES;
    const int* cnt = (blockIdx.x == 0) ? cntE : cntV;
    int* off       = (blockIdx.x == 0) ? offE : offV;
    int* cur       = (blockIdx.x == 0) ? curE : curV;

    __shared__ int wsum[16];
    __shared__ int sh_carry;
    int t = threadIdx.x, lane = t & 63, w = t >> 6;
    if (t == 0) sh_carry = 0;
    __syncthreads();
    for (int base = 0; base < N; base += 1024) {
        int i = base + t;
        int v = (i < N) ? cnt[i] : 0;
        int x = v;
        #pragma unroll
        for (int d = 1; d < 64; d <<= 1) {
            int u = __shfl_up(x, d, 64);
            if (lane >= d) x += u;
        }
        if (lane == 63) wsum[w] = x;
        __syncthreads();
        int c = sh_carry;
        __syncthreads();
        if (t == 0) {
            int acc = 0;
            #pragma unroll
            for (int k = 0; k < 16; ++k) { int tk = wsum[k]; wsum[k] = acc; acc += tk; }
            sh_carry = c + acc;
        }
        __syncthreads();
        if (i < N) {
            int e = c + wsum[w] + (x - v);   // exclusive prefix
            off[i] = e; cur[i] = e;
        }
        __syncthreads();
    }
}

// ---------------- fill CSR adjacency lists ----------------------------------
__global__ void fill_kernel(const int* __restrict__ Vi, const int* __restrict__ Ei,
                            int* __restrict__ curE, int* __restrict__ curV,
                            int* __restrict__ listE, int* __restrict__ listV) {
    int n = blockIdx.x * blockDim.x + threadIdx.x;
    if (n >= NNZ) return;
    int v = Vi[n], e = Ei[n];
    listE[atomicAdd(&curE[e], 1)] = v;
    listV[atomicAdd(&curV[v], 1)] = e;
}

// ------ FUSED segmented mean + stats: persistent grid, no atomics -----------
// 1024 thr = 16 waves; each wave grid-strides destination rows (one row/wave).
// Lane owns column pair (2*lane, 2*lane+1); subspace = lane>>3 (8 lanes).
__global__ __launch_bounds__(1024) void gather_stats(
        const __half* __restrict__ src, __half* __restrict__ dst,
        const int* __restrict__ list, const int* __restrict__ off,
        const int* __restrict__ cnt, int N, float* __restrict__ partials) {
    int t = threadIdx.x;
    int w = t >> 6;
    int lane = t & 63;
    int gw = blockIdx.x * 16 + w;           // global wave id
    const int NW = NBLK * 16;               // total waves
    const __half2* s2 = (const __half2*)src;
    __half2* d2 = (__half2*)dst;

    float ent = 0.f;
    float colx = 0.f, coly = 0.f;
    float g0[16], g1[16];                   // gram rows for my 2 cols x 16 subspace cols
    #pragma unroll
    for (int j = 0; j < 16; ++j) { g0[j] = 0.f; g1[j] = 0.f; }

    for (int row = gw; row < N; row += NW) {
        int o   = off[row];
        int deg = cnt[row];
        float2 a0{0,0}, a1{0,0}, a2{0,0}, a3{0,0}, a4{0,0}, a5{0,0}, a6{0,0}, a7{0,0};
        int k = 0;
        for (; k + 8 <= deg; k += 8) {
            int i0 = list[o+k+0], i1 = list[o+k+1], i2 = list[o+k+2], i3 = list[o+k+3];
            int i4 = list[o+k+4], i5 = list[o+k+5], i6 = list[o+k+6], i7 = list[o+k+7];
            float2 v0 = __half22float2(s2[(size_t)i0*64 + lane]);
            float2 v1 = __half22float2(s2[(size_t)i1*64 + lane]);
            float2 v2 = __half22float2(s2[(size_t)i2*64 + lane]);
            float2 v3 = __half22float2(s2[(size_t)i3*64 + lane]);
            float2 v4 = __half22float2(s2[(size_t)i4*64 + lane]);
            float2 v5 = __half22float2(s2[(size_t)i5*64 + lane]);
            float2 v6 = __half22float2(s2[(size_t)i6*64 + lane]);
            float2 v7 = __half22float2(s2[(size_t)i7*64 + lane]);
            a0.x += v0.x; a0.y += v0.y;  a1.x += v1.x; a1.y += v1.y;
            a2.x += v2.x; a2.y += v2.y;  a3.x += v3.x; a3.y += v3.y;
            a4.x += v4.x; a4.y += v4.y;  a5.x += v5.x; a5.y += v5.y;
            a6.x += v6.x; a6.y += v6.y;  a7.x += v7.x; a7.y += v7.y;
        }
        for (; k < deg; ++k) {
            int i0 = list[o+k];
            float2 v0 = __half22float2(s2[(size_t)i0*64 + lane]);
            a0.x += v0.x; a0.y += v0.y;
        }
        float inv = 1.0f / fmaxf((float)deg, 1.0f);
        float yx = (a0.x+a1.x+a2.x+a3.x+a4.x+a5.x+a6.x+a7.x) * inv;
        float yy = (a0.y+a1.y+a2.y+a3.y+a4.y+a5.y+a6.y+a7.y) * inv;
        d2[(size_t)row*64 + lane] = __floats2half2_rn(yx, yy);

        // stats on the fp32 mean
        ent -= yx * logf(yx + EPSF) + yy * logf(yy + EPSF);
        colx += yx; coly += yy;
        int base = lane & ~7;               // first lane of my subspace group
        #pragma unroll
        for (int jj = 0; jj < 8; ++jj) {
            float zx = __shfl(yx, base + jj, 64);
            float zy = __shfl(yy, base + jj, 64);
            g0[2*jj]   += yx * zx;  g0[2*jj+1] += yx * zy;
            g1[2*jj]   += yy * zx;  g1[2*jj+1] += yy * zy;
        }
    }

    // ---- block reduction into partials[blockIdx.x * STATS_STRIDE] ----------
    float* part = partials + (size_t)blockIdx.x * STATS_STRIDE;
    __shared__ float red[1024];

    // entropy: full block tree reduce
    red[t] = ent; __syncthreads();
    for (int st = 512; st > 0; st >>= 1) {
        if (t < st) red[t] += red[t + st];
        __syncthreads();
    }
    if (t == 0) part[0] = red[0];
    __syncthreads();

    // colsum: lane-l column pair summed across 16 waves
    red[t] = colx; __syncthreads();
    if (t < 64) {
        float v = 0.f;
        #pragma unroll
        for (int k = 0; k < 16; ++k) v += red[k*64 + t];
        part[1 + 2*t] = v;
    }
    __syncthreads();
    red[t] = coly; __syncthreads();
    if (t < 64) {
        float v = 0.f;
        #pragma unroll
        for (int k = 0; k < 16; ++k) v += red[k*64 + t];
        part[1 + 2*t + 1] = v;
    }
    __syncthreads();

    // gram: 32 slices; lane t<64 -> subspace s=t>>3, local rows 2*(t&7)+{0,1}
    for (int j = 0; j < 16; ++j) {
        red[t] = g0[j]; __syncthreads();
        if (t < 64) {
            float v = 0.f;
            #pragma unroll
            for (int k = 0; k < 16; ++k) v += red[k*64 + t];
            part[129 + (t>>3)*256 + (2*(t&7))*16 + j] = v;
        }
        __syncthreads();
        red[t] = g1[j]; __syncthreads();
        if (t < 64) {
            float v = 0.f;
            #pragma unroll
            for (int k = 0; k < 16; ++k) v += red[k*64 + t];
            part[129 + (t>>3)*256 + (2*(t&7)+1)*16 + j] = v;
        }
        __syncthreads();
    }
}

// -------- final partial reduction: all 8 sides at once ----------------------
__global__ void reduce_all_kernel(const float* __restrict__ partials,
                                  float* __restrict__ stats) {
    int u = blockIdx.x * blockDim.x + threadIdx.x;
    if (u >= 8 * STATS_STRIDE) return;
    int side = u / STATS_STRIDE, e = u - side * STATS_STRIDE;
    const float* p = partials + (size_t)side * NBLK * STATS_STRIDE + e;
    float acc = 0.f;
    for (int b = 0; b < NBLK; ++b)
        acc += p[(size_t)b * STATS_STRIDE];
    stats[side * STATS_STRIDE + e] = acc;
}

// ---------------- final loss from the 8 stats blocks ------------------------
__global__ void loss_kernel(const float* __restrict__ stats, float* __restrict__ out) {
    int t = threadIdx.x;
    float acc_l = 0.f, acc_g = 0.f;

    if (t < 8) {
        float N = (t & 1) ? (float)V_NODES : (float)E_EDGES;
        acc_l = stats[t * STATS_STRIDE] / (N * (float)S_SUB);
    }

    for (int u = t; u < 8 * 128; u += blockDim.x) {
        int side = u >> 7, d = u & 127;
        float N = (side & 1) ? (float)V_NODES : (float)E_EDGES;
        float p = stats[side * STATS_STRIDE + 1 + d] / N;
        acc_g += p * logf(p + EPSF) / (float)S_SUB;
    }

    for (int u = t; u < 8 * 8 * 16; u += blockDim.x) {
        int side = u >> 7;
        int s = (u >> 4) & 7;
        int i = u & 15;
        const float* G = stats + side * STATS_STRIDE + 129 + s * 256;
        float nii = sqrtf(G[i * 16 + i]);
        float C[16];
        float m = -INFINITY;
        #pragma unroll
        for (int j = 0; j < 16; ++j) {
            float njj = sqrtf(G[j * 16 + j]);
            float c = G[i * 16 + j] / fmaxf(nii * njj, EPSF);
            C[j] = c;
            m = fmaxf(m, c);
        }
        float sum = 0.f;
        #pragma unroll
        for (int j = 0; j < 16; ++j) sum += expf(C[j] - m);
        float lse = logf(sum) + m;
        acc_g += (lse - C[i]) / (float)(S_SUB * K_SUB);
    }

    __shared__ float redl[256], redg[256];
    redl[t] = acc_l; redg[t] = acc_g; __syncthreads();
    for (int st = 128; st > 0; st >>= 1) {
        if (t < st) { redl[t] += redl[t + st]; redg[t] += redg[t + st]; }
        __syncthreads();
    }
    if (t == 0) { out[0] = redl[0]; out[1] = redg[0]; }
}

extern "C" void kernel_launch(void* const* d_in, const int* in_sizes, int n_in,
                              void* d_out, int out_size, void* d_ws, size_t ws_size,
                              hipStream_t stream) {
    const float* emb = (const float*)d_in[0];
    const float* gum = (const float*)d_in[1];
    const int*   Vi  = (const int*)d_in[2];
    const int*   Ei  = (const int*)d_in[3];
    float* out = (float*)d_out;

    char* ws = (char*)d_ws;
    size_t off = 0;
    __half* X = (__half*)(ws + off);    off += (size_t)V_NODES * DD * 2;   // 12.8 MB
    __half* Y = (__half*)(ws + off);    off += (size_t)E_EDGES * DD * 2;   // 6.4 MB
    int* listE = (int*)(ws + off);      off += (size_t)NNZ * 4;            // 2.4 MB
    int* listV = (int*)(ws + off);      off += (size_t)NNZ * 4;            // 2.4 MB
    int* cntE  = (int*)(ws + off);      off += (size_t)E_EDGES * 4;
    int* cntV  = (int*)(ws + off);      off += (size_t)V_NODES * 4;
    int* offE  = (int*)(ws + off);      off += (size_t)E_EDGES * 4;
    int* offV  = (int*)(ws + off);      off += (size_t)V_NODES * 4;
    int* curE  = (int*)(ws + off);      off += (size_t)E_EDGES * 4;
    int* curV  = (int*)(ws + off);      off += (size_t)V_NODES * 4;
    float* stats = (float*)(ws + off);  off += (size_t)8 * STATS_STRIDE * 4;
    float* partials = (float*)(ws + off);
    off += (size_t)8 * NBLK * STATS_STRIDE * 4;                            // 17.8 MB

    // zero counts (hist accumulates); everything else fully overwritten
    hipMemsetAsync(cntE, 0, ((size_t)E_EDGES + V_NODES) * 4, stream);

    softmax16_kernel<<<(V_NODES * 64 + 255) / 256, 256, 0, stream>>>(emb, gum, X);
    hist_kernel<<<(NNZ + 255) / 256, 256, 0, stream>>>(Vi, Ei, cntV, cntE);
    scan2_kernel<<<2, 1024, 0, stream>>>(cntE, cntV, offE, offV, curE, curV);
    fill_kernel<<<(NNZ + 255) / 256, 256, 0, stream>>>(Vi, Ei, curE, curV, listE, listV);

    const size_t PSIDE = (size_t)NBLK * STATS_STRIDE;
    for (int step = 0; step < NUM_STEP; ++step) {
        gather_stats<<<NBLK, 1024, 0, stream>>>(X, Y, listE, offE, cntE, E_EDGES,
                                                partials + (2*step) * PSIDE);
        gather_stats<<<NBLK, 1024, 0, stream>>>(Y, X, listV, offV, cntV, V_NODES,
                                                partials + (2*step + 1) * PSIDE);
    }

    reduce_all_kernel<<<(8 * STATS_STRIDE + 255) / 256, 256, 0, stream>>>(partials, stats);
    loss_kernel<<<1, 256, 0, stream>>>(stats, out);
}

// Round 9
// 597.660 us; speedup vs baseline: 6.4532x; 1.0615x over previous
//
#include <hip/hip_runtime.h>
#include <hip/hip_bf16.h>
#include <hip/hip_fp16.h>
#include <math.h>

#define V_NODES 50000
#define E_EDGES 25000
#define NNZ     600000
#define S_SUB   8
#define K_SUB   16
#define DD      128      // S*K
#define NUM_STEP 4
#define EPSF    1e-10f

// stats layout per side (side = 2*step + {0:Y,1:X}), stride 2177 floats:
// [0] entropy sum; [1..128] colsum; [129..2176] gram (s*256 + i*16 + j)
#define STATS_STRIDE 2177
#define NBLK 256         // fused gather+stats grid (1 block/CU, 16 waves)

// scan tiling: 25 tiles of E, 49 tiles of V (1024 elements each)
#define NTILE_E 25
#define NTILE_V 49
#define NTILES  (NTILE_E + NTILE_V)

// ----- manual fp8-e4m3 pair (values are NON-NEGATIVE probabilities) --------
// decode: f8 bits<<7 as f16, *256 (exact for normals+subnormals, sign=0)
// encode: f32 -> f16(x/256) -> RNE shift >>7
typedef unsigned short pack_t;   // 2 fp8 values (2 adjacent columns)

__device__ inline float2 unpack2(pack_t u) {
    unsigned int bits = ((unsigned)(u & 0x7f) << 7) | ((unsigned)(u & 0x7f00) << 15);
    __half2 h2 = __builtin_bit_cast(__half2, bits);
    float2 v = __half22float2(h2);
    return float2{v.x * 256.0f, v.y * 256.0f};
}
__device__ inline pack_t pack2(float a, float b) {
    unsigned short ha = __half_as_ushort(__float2half_rn(a * 0.00390625f));
    unsigned short hb = __half_as_ushort(__float2half_rn(b * 0.00390625f));
    unsigned short ra = (unsigned short)((ha + 0x3F + ((ha >> 7) & 1)) >> 7);
    unsigned short rb = (unsigned short)((hb + 0x3F + ((hb >> 7) & 1)) >> 7);
    return (pack_t)(ra | (rb << 8));
}

// ------- softmax over groups of 16 cols (gumbel-softmax X0), fp8 out --------
__global__ void softmax16_kernel(const float* __restrict__ emb,
                                 const float* __restrict__ gum,
                                 pack_t* __restrict__ X) {
    int i2 = blockIdx.x * blockDim.x + threadIdx.x;   // pair index
    if (i2 >= V_NODES * 64) return;
    const float2* e2 = (const float2*)emb;
    const float2* g2 = (const float2*)gum;
    float2 e = e2[i2], g = g2[i2];
    float xa = e.x + g.x, xb = e.y + g.y;   // TAU = 1.0
    float m = fmaxf(xa, xb);
    #pragma unroll
    for (int off = 1; off < 8; off <<= 1) m = fmaxf(m, __shfl_xor(m, off, 8));
    float ea = expf(xa - m), eb = expf(xb - m);
    float s = ea + eb;
    #pragma unroll
    for (int off = 1; off < 8; off <<= 1) s += __shfl_xor(s, off, 8);
    float inv = 1.0f / s;
    X[i2] = pack2(ea * inv, eb * inv);
}

// ---------------- int histogram of segment counts ---------------------------
__global__ void hist_kernel(const int* __restrict__ Vi, const int* __restrict__ Ei,
                            int* __restrict__ cntV, int* __restrict__ cntE) {
    int n = blockIdx.x * blockDim.x + threadIdx.x;
    if (n >= NNZ) return;
    atomicAdd(&cntV[Vi[n]], 1);
    atomicAdd(&cntE[Ei[n]], 1);
}

// ---------------- multi-block scan: stage A (tile-local scan + tile sum) ----
__global__ void scanA_kernel(const int* __restrict__ cntE, const int* __restrict__ cntV,
                             int* __restrict__ offE, int* __restrict__ offV,
                             int* __restrict__ sums) {
    int b = blockIdx.x;
    bool isE = b < NTILE_E;
    const int* cnt = isE ? cntE : cntV;
    int* off       = isE ? offE : offV;
    int N          = isE ? E_EDGES : V_NODES;
    int tile       = isE ? b : b - NTILE_E;

    int t = threadIdx.x, lane = t & 63, w = t >> 6;
    int i = tile * 1024 + t;
    int v = (i < N) ? cnt[i] : 0;
    int x = v;
    #pragma unroll
    for (int d = 1; d < 64; d <<= 1) {
        int u = __shfl_up(x, d, 64);
        if (lane >= d) x += u;
    }
    __shared__ int wsum[16];
    if (lane == 63) wsum[w] = x;
    __syncthreads();
    if (t == 0) {
        int acc = 0;
        #pragma unroll
        for (int k = 0; k < 16; ++k) { int tk = wsum[k]; wsum[k] = acc; acc += tk; }
    }
    __syncthreads();
    int excl = wsum[w] + x - v;
    if (i < N) off[i] = excl;
    if (t == 1023) sums[b] = excl + v;
}

// ---------------- scan stage B: serial scan of 74 tile sums -----------------
__global__ void scanB_kernel(int* __restrict__ sums) {
    if (threadIdx.x == 0) {
        int acc = 0;
        for (int k = 0; k < NTILE_E; ++k) { int t = sums[k]; sums[k] = acc; acc += t; }
        acc = 0;
        for (int k = NTILE_E; k < NTILES; ++k) { int t = sums[k]; sums[k] = acc; acc += t; }
    }
}

// ---------------- scan stage C: add tile base, emit off + cur ---------------
__global__ void scanC_kernel(int* __restrict__ offE, int* __restrict__ offV,
                             const int* __restrict__ sums,
                             int* __restrict__ curE, int* __restrict__ curV) {
    int b = blockIdx.x;
    bool isE = b < NTILE_E;
    int* off = isE ? offE : offV;
    int* cur = isE ? curE : curV;
    int N    = isE ? E_EDGES : V_NODES;
    int tile = isE ? b : b - NTILE_E;
    int i = tile * 1024 + threadIdx.x;
    if (i < N) {
        int e = off[i] + sums[b];
        off[i] = e;
        cur[i] = e;
    }
}

// ---------------- fill CSR adjacency lists (nontemporal stores) -------------
__global__ void fill_kernel(const int* __restrict__ Vi, const int* __restrict__ Ei,
                            int* __restrict__ curE, int* __restrict__ curV,
                            int* __restrict__ listE, int* __restrict__ listV) {
    int n = blockIdx.x * blockDim.x + threadIdx.x;
    if (n >= NNZ) return;
    int v = Vi[n], e = Ei[n];
    int se = atomicAdd(&curE[e], 1);
    int sv = atomicAdd(&curV[v], 1);
    __builtin_nontemporal_store(v, &listE[se]);
    __builtin_nontemporal_store(e, &listV[sv]);
}

// ------ FUSED segmented mean + stats: persistent grid, no atomics -----------
// 1024 thr = 16 waves; each wave grid-strides destination rows (one row/wave).
// Lane owns column pair (2*lane, 2*lane+1); subspace = lane>>3 (8 lanes).
__global__ __launch_bounds__(1024) void gather_stats(
        const pack_t* __restrict__ src, pack_t* __restrict__ dst,
        const int* __restrict__ list, const int* __restrict__ off,
        const int* __restrict__ cnt, int N, float* __restrict__ partials) {
    int t = threadIdx.x;
    int w = t >> 6;
    int lane = t & 63;
    int gw = blockIdx.x * 16 + w;           // global wave id
    const int NW = NBLK * 16;               // total waves

    float ent = 0.f;
    float colx = 0.f, coly = 0.f;
    float g0[16], g1[16];                   // gram rows for my 2 cols x 16 subspace cols
    #pragma unroll
    for (int j = 0; j < 16; ++j) { g0[j] = 0.f; g1[j] = 0.f; }

    for (int row = gw; row < N; row += NW) {
        int o   = off[row];
        int deg = cnt[row];
        float2 a0{0,0}, a1{0,0}, a2{0,0}, a3{0,0}, a4{0,0}, a5{0,0}, a6{0,0}, a7{0,0};
        int k = 0;
        for (; k + 8 <= deg; k += 8) {
            int i0 = list[o+k+0], i1 = list[o+k+1], i2 = list[o+k+2], i3 = list[o+k+3];
            int i4 = list[o+k+4], i5 = list[o+k+5], i6 = list[o+k+6], i7 = list[o+k+7];
            float2 v0 = unpack2(src[(size_t)i0*64 + lane]);
            float2 v1 = unpack2(src[(size_t)i1*64 + lane]);
            float2 v2 = unpack2(src[(size_t)i2*64 + lane]);
            float2 v3 = unpack2(src[(size_t)i3*64 + lane]);
            float2 v4 = unpack2(src[(size_t)i4*64 + lane]);
            float2 v5 = unpack2(src[(size_t)i5*64 + lane]);
            float2 v6 = unpack2(src[(size_t)i6*64 + lane]);
            float2 v7 = unpack2(src[(size_t)i7*64 + lane]);
            a0.x += v0.x; a0.y += v0.y;  a1.x += v1.x; a1.y += v1.y;
            a2.x += v2.x; a2.y += v2.y;  a3.x += v3.x; a3.y += v3.y;
            a4.x += v4.x; a4.y += v4.y;  a5.x += v5.x; a5.y += v5.y;
            a6.x += v6.x; a6.y += v6.y;  a7.x += v7.x; a7.y += v7.y;
        }
        for (; k < deg; ++k) {
            int i0 = list[o+k];
            float2 v0 = unpack2(src[(size_t)i0*64 + lane]);
            a0.x += v0.x; a0.y += v0.y;
        }
        float inv = 1.0f / fmaxf((float)deg, 1.0f);
        float yx = (a0.x+a1.x+a2.x+a3.x+a4.x+a5.x+a6.x+a7.x) * inv;
        float yy = (a0.y+a1.y+a2.y+a3.y+a4.y+a5.y+a6.y+a7.y) * inv;
        dst[(size_t)row*64 + lane] = pack2(yx, yy);

        // stats on the fp32 mean
        ent -= yx * logf(yx + EPSF) + yy * logf(yy + EPSF);
        colx += yx; coly += yy;
        int base = lane & ~7;               // first lane of my subspace group
        #pragma unroll
        for (int jj = 0; jj < 8; ++jj) {
            float zx = __shfl(yx, base + jj, 64);
            float zy = __shfl(yy, base + jj, 64);
            g0[2*jj]   += yx * zx;  g0[2*jj+1] += yx * zy;
            g1[2*jj]   += yy * zx;  g1[2*jj+1] += yy * zy;
        }
    }

    // ---- block reduction into partials[blockIdx.x * STATS_STRIDE] ----------
    float* part = partials + (size_t)blockIdx.x * STATS_STRIDE;
    __shared__ float red[1024];

    // entropy: full block tree reduce
    red[t] = ent; __syncthreads();
    for (int st = 512; st > 0; st >>= 1) {
        if (t < st) red[t] += red[t + st];
        __syncthreads();
    }
    if (t == 0) part[0] = red[0];
    __syncthreads();

    // colsum: lane-l column pair summed across 16 waves
    red[t] = colx; __syncthreads();
    if (t < 64) {
        float v = 0.f;
        #pragma unroll
        for (int k = 0; k < 16; ++k) v += red[k*64 + t];
        part[1 + 2*t] = v;
    }
    __syncthreads();
    red[t] = coly; __syncthreads();
    if (t < 64) {
        float v = 0.f;
        #pragma unroll
        for (int k = 0; k < 16; ++k) v += red[k*64 + t];
        part[1 + 2*t + 1] = v;
    }
    __syncthreads();

    // gram: 32 slices; lane t<64 -> subspace s=t>>3, local rows 2*(t&7)+{0,1}
    for (int j = 0; j < 16; ++j) {
        red[t] = g0[j]; __syncthreads();
        if (t < 64) {
            float v = 0.f;
            #pragma unroll
            for (int k = 0; k < 16; ++k) v += red[k*64 + t];
            part[129 + (t>>3)*256 + (2*(t&7))*16 + j] = v;
        }
        __syncthreads();
        red[t] = g1[j]; __syncthreads();
        if (t < 64) {
            float v = 0.f;
            #pragma unroll
            for (int k = 0; k < 16; ++k) v += red[k*64 + t];
            part[129 + (t>>3)*256 + (2*(t&7)+1)*16 + j] = v;
        }
        __syncthreads();
    }
}

// -------- final partial reduction: all 8 sides at once ----------------------
__global__ void reduce_all_kernel(const float* __restrict__ partials,
                                  float* __restrict__ stats) {
    int u = blockIdx.x * blockDim.x + threadIdx.x;
    if (u >= 8 * STATS_STRIDE) return;
    int side = u / STATS_STRIDE, e = u - side * STATS_STRIDE;
    const float* p = partials + (size_t)side * NBLK * STATS_STRIDE + e;
    float acc = 0.f;
    for (int b = 0; b < NBLK; ++b)
        acc += p[(size_t)b * STATS_STRIDE];
    stats[side * STATS_STRIDE + e] = acc;
}

// ---------------- final loss from the 8 stats blocks ------------------------
__global__ void loss_kernel(const float* __restrict__ stats, float* __restrict__ out) {
    int t = threadIdx.x;
    float acc_l = 0.f, acc_g = 0.f;

    if (t < 8) {
        float N = (t & 1) ? (float)V_NODES : (float)E_EDGES;
        acc_l = stats[t * STATS_STRIDE] / (N * (float)S_SUB);
    }

    for (int u = t; u < 8 * 128; u += blockDim.x) {
        int side = u >> 7, d = u & 127;
        float N = (side & 1) ? (float)V_NODES : (float)E_EDGES;
        float p = stats[side * STATS_STRIDE + 1 + d] / N;
        acc_g += p * logf(p + EPSF) / (float)S_SUB;
    }

    for (int u = t; u < 8 * 8 * 16; u += blockDim.x) {
        int side = u >> 7;
        int s = (u >> 4) & 7;
        int i = u & 15;
        const float* G = stats + side * STATS_STRIDE + 129 + s * 256;
        float nii = sqrtf(G[i * 16 + i]);
        float C[16];
        float m = -INFINITY;
        #pragma unroll
        for (int j = 0; j < 16; ++j) {
            float njj = sqrtf(G[j * 16 + j]);
            float c = G[i * 16 + j] / fmaxf(nii * njj, EPSF);
            C[j] = c;
            m = fmaxf(m, c);
        }
        float sum = 0.f;
        #pragma unroll
        for (int j = 0; j < 16; ++j) sum += expf(C[j] - m);
        float lse = logf(sum) + m;
        acc_g += (lse - C[i]) / (float)(S_SUB * K_SUB);
    }

    __shared__ float redl[256], redg[256];
    redl[t] = acc_l; redg[t] = acc_g; __syncthreads();
    for (int st = 128; st > 0; st >>= 1) {
        if (t < st) { redl[t] += redl[t + st]; redg[t] += redg[t + st]; }
        __syncthreads();
    }
    if (t == 0) { out[0] = redl[0]; out[1] = redg[0]; }
}

extern "C" void kernel_launch(void* const* d_in, const int* in_sizes, int n_in,
                              void* d_out, int out_size, void* d_ws, size_t ws_size,
                              hipStream_t stream) {
    const float* emb = (const float*)d_in[0];
    const float* gum = (const float*)d_in[1];
    const int*   Vi  = (const int*)d_in[2];
    const int*   Ei  = (const int*)d_in[3];
    float* out = (float*)d_out;

    char* ws = (char*)d_ws;
    size_t off = 0;
    pack_t* X = (pack_t*)(ws + off);    off += (size_t)V_NODES * 64 * sizeof(pack_t); // 6.4 MB
    pack_t* Y = (pack_t*)(ws + off);    off += (size_t)E_EDGES * 64 * sizeof(pack_t); // 3.2 MB
    int* listE = (int*)(ws + off);      off += (size_t)NNZ * 4;            // 2.4 MB
    int* listV = (int*)(ws + off);      off += (size_t)NNZ * 4;            // 2.4 MB
    int* cntE  = (int*)(ws + off);      off += (size_t)E_EDGES * 4;
    int* cntV  = (int*)(ws + off);      off += (size_t)V_NODES * 4;
    int* offE  = (int*)(ws + off);      off += (size_t)E_EDGES * 4;
    int* offV  = (int*)(ws + off);      off += (size_t)V_NODES * 4;
    int* curE  = (int*)(ws + off);      off += (size_t)E_EDGES * 4;
    int* curV  = (int*)(ws + off);      off += (size_t)V_NODES * 4;
    int* sums  = (int*)(ws + off);      off += (size_t)NTILES * 4;
    float* stats = (float*)(ws + off);  off += (size_t)8 * STATS_STRIDE * 4;
    float* partials = (float*)(ws + off);
    off += (size_t)8 * NBLK * STATS_STRIDE * 4;                            // 17.8 MB

    // zero counts (hist accumulates); everything else fully overwritten
    hipMemsetAsync(cntE, 0, ((size_t)E_EDGES + V_NODES) * 4, stream);

    softmax16_kernel<<<(V_NODES * 64 + 255) / 256, 256, 0, stream>>>(emb, gum, X);
    hist_kernel<<<(NNZ + 255) / 256, 256, 0, stream>>>(Vi, Ei, cntV, cntE);
    scanA_kernel<<<NTILES, 1024, 0, stream>>>(cntE, cntV, offE, offV, sums);
    scanB_kernel<<<1, 64, 0, stream>>>(sums);
    scanC_kernel<<<NTILES, 1024, 0, stream>>>(offE, offV, sums, curE, curV);
    fill_kernel<<<(NNZ + 255) / 256, 256, 0, stream>>>(Vi, Ei, curE, curV, listE, listV);

    const size_t PSIDE = (size_t)NBLK * STATS_STRIDE;
    for (int step = 0; step < NUM_STEP; ++step) {
        gather_stats<<<NBLK, 1024, 0, stream>>>(X, Y, listE, offE, cntE, E_EDGES,
                                                partials + (2*step) * PSIDE);
        gather_stats<<<NBLK, 1024, 0, stream>>>(Y, X, listV, offV, cntV, V_NODES,
                                                partials + (2*step + 1) * PSIDE);
    }

    reduce_all_kernel<<<(8 * STATS_STRIDE + 255) / 256, 256, 0, stream>>>(partials, stats);
    loss_kernel<<<1, 256, 0, stream>>>(stats, out);
}

// Round 10
// 545.470 us; speedup vs baseline: 7.0707x; 1.0957x over previous
//
#include <hip/hip_runtime.h>
#include <hip/hip_bf16.h>
#include <hip/hip_fp16.h>
#include <math.h>

#define V_NODES 50000
#define E_EDGES 25000
#define NNZ     600000
#define S_SUB   8
#define K_SUB   16
#define DD      128      // S*K
#define NUM_STEP 4
#define EPSF    1e-10f

// stats layout per side (side = 2*step + {0:Y,1:X}), stride 2177 floats:
// [0] entropy sum; [1..128] colsum; [129..2176] gram (s*256 + i*16 + j)
#define STATS_STRIDE 2177
#define NBLK 256         // fused gather+stats grid (1 block/CU, 16 waves)

// scan tiling: 25 tiles of E, 49 tiles of V (1024 elements each)
#define NTILE_E 25
#define NTILE_V 49
#define NTILES  (NTILE_E + NTILE_V)

// fill partitioning: 8 groups (presumed XCDs), 256 blocks per group
#define FILL_BPG 256

// ----- manual fp8-e4m3 pair (values are NON-NEGATIVE probabilities) --------
// decode: f8 bits<<7 as f16, *256 (exact for normals+subnormals, sign=0)
// encode: f32 -> f16(x/256) -> RNE shift >>7
typedef unsigned short pack_t;   // 2 fp8 values (2 adjacent columns)

__device__ inline float2 unpack2(pack_t u) {
    unsigned int bits = ((unsigned)(u & 0x7f) << 7) | ((unsigned)(u & 0x7f00) << 15);
    __half2 h2 = __builtin_bit_cast(__half2, bits);
    float2 v = __half22float2(h2);
    return float2{v.x * 256.0f, v.y * 256.0f};
}
__device__ inline pack_t pack2(float a, float b) {
    unsigned short ha = __half_as_ushort(__float2half_rn(a * 0.00390625f));
    unsigned short hb = __half_as_ushort(__float2half_rn(b * 0.00390625f));
    unsigned short ra = (unsigned short)((ha + 0x3F + ((ha >> 7) & 1)) >> 7);
    unsigned short rb = (unsigned short)((hb + 0x3F + ((hb >> 7) & 1)) >> 7);
    return (pack_t)(ra | (rb << 8));
}

// ------- softmax over groups of 16 cols (gumbel-softmax X0), fp8 out --------
__global__ void softmax16_kernel(const float* __restrict__ emb,
                                 const float* __restrict__ gum,
                                 pack_t* __restrict__ X) {
    int i2 = blockIdx.x * blockDim.x + threadIdx.x;   // pair index
    if (i2 >= V_NODES * 64) return;
    const float2* e2 = (const float2*)emb;
    const float2* g2 = (const float2*)gum;
    float2 e = e2[i2], g = g2[i2];
    float xa = e.x + g.x, xb = e.y + g.y;   // TAU = 1.0
    float m = fmaxf(xa, xb);
    #pragma unroll
    for (int off = 1; off < 8; off <<= 1) m = fmaxf(m, __shfl_xor(m, off, 8));
    float ea = expf(xa - m), eb = expf(xb - m);
    float s = ea + eb;
    #pragma unroll
    for (int off = 1; off < 8; off <<= 1) s += __shfl_xor(s, off, 8);
    float inv = 1.0f / s;
    X[i2] = pack2(ea * inv, eb * inv);
}

// ---------------- int histogram of segment counts ---------------------------
__global__ void hist_kernel(const int* __restrict__ Vi, const int* __restrict__ Ei,
                            int* __restrict__ cntV, int* __restrict__ cntE) {
    int n = blockIdx.x * blockDim.x + threadIdx.x;
    if (n >= NNZ) return;
    atomicAdd(&cntV[Vi[n]], 1);
    atomicAdd(&cntE[Ei[n]], 1);
}

// ---------------- multi-block scan: stage A (tile-local scan + tile sum) ----
__global__ void scanA_kernel(const int* __restrict__ cntE, const int* __restrict__ cntV,
                             int* __restrict__ offE, int* __restrict__ offV,
                             int* __restrict__ sums) {
    int b = blockIdx.x;
    bool isE = b < NTILE_E;
    const int* cnt = isE ? cntE : cntV;
    int* off       = isE ? offE : offV;
    int N          = isE ? E_EDGES : V_NODES;
    int tile       = isE ? b : b - NTILE_E;

    int t = threadIdx.x, lane = t & 63, w = t >> 6;
    int i = tile * 1024 + t;
    int v = (i < N) ? cnt[i] : 0;
    int x = v;
    #pragma unroll
    for (int d = 1; d < 64; d <<= 1) {
        int u = __shfl_up(x, d, 64);
        if (lane >= d) x += u;
    }
    __shared__ int wsum[16];
    if (lane == 63) wsum[w] = x;
    __syncthreads();
    if (t == 0) {
        int acc = 0;
        #pragma unroll
        for (int k = 0; k < 16; ++k) { int tk = wsum[k]; wsum[k] = acc; acc += tk; }
    }
    __syncthreads();
    int excl = wsum[w] + x - v;
    if (i < N) off[i] = excl;
    if (t == 1023) sums[b] = excl + v;
}

// ---------------- scan stage B: serial scan of 74 tile sums -----------------
__global__ void scanB_kernel(int* __restrict__ sums) {
    if (threadIdx.x == 0) {
        int acc = 0;
        for (int k = 0; k < NTILE_E; ++k) { int t = sums[k]; sums[k] = acc; acc += t; }
        acc = 0;
        for (int k = NTILE_E; k < NTILES; ++k) { int t = sums[k]; sums[k] = acc; acc += t; }
    }
}

// ---------------- scan stage C: add tile base, emit off + cur ---------------
__global__ void scanC_kernel(int* __restrict__ offE, int* __restrict__ offV,
                             const int* __restrict__ sums,
                             int* __restrict__ curE, int* __restrict__ curV) {
    int b = blockIdx.x;
    bool isE = b < NTILE_E;
    int* off = isE ? offE : offV;
    int* cur = isE ? curE : curV;
    int N    = isE ? E_EDGES : V_NODES;
    int tile = isE ? b : b - NTILE_E;
    int i = tile * 1024 + threadIdx.x;
    if (i < N) {
        int e = off[i] + sums[b];
        off[i] = e;
        cur[i] = e;
    }
}

// ------- fill CSR lists, XCD-partitioned by destination range ---------------
// group g = blockIdx&7 (presumed XCD id under round-robin dispatch) handles
// destinations in its 1/8 range only -> every list line written by one XCD,
// merges in that XCD's L2. ushort payload (ids < 65536).
__global__ void fill_kernel(const int* __restrict__ Vi, const int* __restrict__ Ei,
                            int* __restrict__ curE, int* __restrict__ curV,
                            unsigned short* __restrict__ listE,
                            unsigned short* __restrict__ listV) {
    int g  = blockIdx.x & 7;
    int bg = blockIdx.x >> 3;
    int eLo = g * (E_EDGES / 8), eHi = eLo + (E_EDGES / 8);
    int vLo = g * (V_NODES / 8), vHi = vLo + (V_NODES / 8);
    for (int n = bg * 256 + threadIdx.x; n < NNZ; n += FILL_BPG * 256) {
        int e = Ei[n], v = Vi[n];
        if (e >= eLo && e < eHi)
            listE[atomicAdd(&curE[e], 1)] = (unsigned short)v;
        if (v >= vLo && v < vHi)
            listV[atomicAdd(&curV[v], 1)] = (unsigned short)e;
    }
}

// ------ FUSED segmented mean + stats: persistent grid, no atomics -----------
// 1024 thr = 16 waves; each wave grid-strides destination rows (one row/wave).
// Lane owns column pair (2*lane, 2*lane+1); subspace = lane>>3 (8 lanes).
__global__ __launch_bounds__(1024) void gather_stats(
        const pack_t* __restrict__ src, pack_t* __restrict__ dst,
        const unsigned short* __restrict__ list, const int* __restrict__ off,
        const int* __restrict__ cnt, int N, float* __restrict__ partials) {
    int t = threadIdx.x;
    int w = t >> 6;
    int lane = t & 63;
    int gw = blockIdx.x * 16 + w;           // global wave id
    const int NW = NBLK * 16;               // total waves

    float ent = 0.f;
    float colx = 0.f, coly = 0.f;
    float g0[16], g1[16];                   // gram rows for my 2 cols x 16 subspace cols
    #pragma unroll
    for (int j = 0; j < 16; ++j) { g0[j] = 0.f; g1[j] = 0.f; }

    for (int row = gw; row < N; row += NW) {
        int o   = off[row];
        int deg = cnt[row];
        float2 a0{0,0}, a1{0,0}, a2{0,0}, a3{0,0}, a4{0,0}, a5{0,0}, a6{0,0}, a7{0,0};
        int k = 0;
        for (; k + 8 <= deg; k += 8) {
            int i0 = list[o+k+0], i1 = list[o+k+1], i2 = list[o+k+2], i3 = list[o+k+3];
            int i4 = list[o+k+4], i5 = list[o+k+5], i6 = list[o+k+6], i7 = list[o+k+7];
            float2 v0 = unpack2(src[(size_t)i0*64 + lane]);
            float2 v1 = unpack2(src[(size_t)i1*64 + lane]);
            float2 v2 = unpack2(src[(size_t)i2*64 + lane]);
            float2 v3 = unpack2(src[(size_t)i3*64 + lane]);
            float2 v4 = unpack2(src[(size_t)i4*64 + lane]);
            float2 v5 = unpack2(src[(size_t)i5*64 + lane]);
            float2 v6 = unpack2(src[(size_t)i6*64 + lane]);
            float2 v7 = unpack2(src[(size_t)i7*64 + lane]);
            a0.x += v0.x; a0.y += v0.y;  a1.x += v1.x; a1.y += v1.y;
            a2.x += v2.x; a2.y += v2.y;  a3.x += v3.x; a3.y += v3.y;
            a4.x += v4.x; a4.y += v4.y;  a5.x += v5.x; a5.y += v5.y;
            a6.x += v6.x; a6.y += v6.y;  a7.x += v7.x; a7.y += v7.y;
        }
        for (; k < deg; ++k) {
            int i0 = list[o+k];
            float2 v0 = unpack2(src[(size_t)i0*64 + lane]);
            a0.x += v0.x; a0.y += v0.y;
        }
        float inv = 1.0f / fmaxf((float)deg, 1.0f);
        float yx = (a0.x+a1.x+a2.x+a3.x+a4.x+a5.x+a6.x+a7.x) * inv;
        float yy = (a0.y+a1.y+a2.y+a3.y+a4.y+a5.y+a6.y+a7.y) * inv;
        dst[(size_t)row*64 + lane] = pack2(yx, yy);

        // stats on the fp32 mean
        ent -= yx * logf(yx + EPSF) + yy * logf(yy + EPSF);
        colx += yx; coly += yy;
        int base = lane & ~7;               // first lane of my subspace group
        #pragma unroll
        for (int jj = 0; jj < 8; ++jj) {
            float zx = __shfl(yx, base + jj, 64);
            float zy = __shfl(yy, base + jj, 64);
            g0[2*jj]   += yx * zx;  g0[2*jj+1] += yx * zy;
            g1[2*jj]   += yy * zx;  g1[2*jj+1] += yy * zy;
        }
    }

    // ---- block reduction into partials[blockIdx.x * STATS_STRIDE] ----------
    float* part = partials + (size_t)blockIdx.x * STATS_STRIDE;
    __shared__ float red[1024];

    // entropy: full block tree reduce
    red[t] = ent; __syncthreads();
    for (int st = 512; st > 0; st >>= 1) {
        if (t < st) red[t] += red[t + st];
        __syncthreads();
    }
    if (t == 0) part[0] = red[0];
    __syncthreads();

    // colsum: lane-l column pair summed across 16 waves
    red[t] = colx; __syncthreads();
    if (t < 64) {
        float v = 0.f;
        #pragma unroll
        for (int k = 0; k < 16; ++k) v += red[k*64 + t];
        part[1 + 2*t] = v;
    }
    __syncthreads();
    red[t] = coly; __syncthreads();
    if (t < 64) {
        float v = 0.f;
        #pragma unroll
        for (int k = 0; k < 16; ++k) v += red[k*64 + t];
        part[1 + 2*t + 1] = v;
    }
    __syncthreads();

    // gram: 32 slices; lane t<64 -> subspace s=t>>3, local rows 2*(t&7)+{0,1}
    for (int j = 0; j < 16; ++j) {
        red[t] = g0[j]; __syncthreads();
        if (t < 64) {
            float v = 0.f;
            #pragma unroll
            for (int k = 0; k < 16; ++k) v += red[k*64 + t];
            part[129 + (t>>3)*256 + (2*(t&7))*16 + j] = v;
        }
        __syncthreads();
        red[t] = g1[j]; __syncthreads();
        if (t < 64) {
            float v = 0.f;
            #pragma unroll
            for (int k = 0; k < 16; ++k) v += red[k*64 + t];
            part[129 + (t>>3)*256 + (2*(t&7)+1)*16 + j] = v;
        }
        __syncthreads();
    }
}

// -------- final partial reduction: all 8 sides at once ----------------------
__global__ void reduce_all_kernel(const float* __restrict__ partials,
                                  float* __restrict__ stats) {
    int u = blockIdx.x * blockDim.x + threadIdx.x;
    if (u >= 8 * STATS_STRIDE) return;
    int side = u / STATS_STRIDE, e = u - side * STATS_STRIDE;
    const float* p = partials + (size_t)side * NBLK * STATS_STRIDE + e;
    float acc = 0.f;
    for (int b = 0; b < NBLK; ++b)
        acc += p[(size_t)b * STATS_STRIDE];
    stats[side * STATS_STRIDE + e] = acc;
}

// ---------------- final loss from the 8 stats blocks ------------------------
__global__ void loss_kernel(const float* __restrict__ stats, float* __restrict__ out) {
    int t = threadIdx.x;
    float acc_l = 0.f, acc_g = 0.f;

    if (t < 8) {
        float N = (t & 1) ? (float)V_NODES : (float)E_EDGES;
        acc_l = stats[t * STATS_STRIDE] / (N * (float)S_SUB);
    }

    for (int u = t; u < 8 * 128; u += blockDim.x) {
        int side = u >> 7, d = u & 127;
        float N = (side & 1) ? (float)V_NODES : (float)E_EDGES;
        float p = stats[side * STATS_STRIDE + 1 + d] / N;
        acc_g += p * logf(p + EPSF) / (float)S_SUB;
    }

    for (int u = t; u < 8 * 8 * 16; u += blockDim.x) {
        int side = u >> 7;
        int s = (u >> 4) & 7;
        int i = u & 15;
        const float* G = stats + side * STATS_STRIDE + 129 + s * 256;
        float nii = sqrtf(G[i * 16 + i]);
        float C[16];
        float m = -INFINITY;
        #pragma unroll
        for (int j = 0; j < 16; ++j) {
            float njj = sqrtf(G[j * 16 + j]);
            float c = G[i * 16 + j] / fmaxf(nii * njj, EPSF);
            C[j] = c;
            m = fmaxf(m, c);
        }
        float sum = 0.f;
        #pragma unroll
        for (int j = 0; j < 16; ++j) sum += expf(C[j] - m);
        float lse = logf(sum) + m;
        acc_g += (lse - C[i]) / (float)(S_SUB * K_SUB);
    }

    __shared__ float redl[256], redg[256];
    redl[t] = acc_l; redg[t] = acc_g; __syncthreads();
    for (int st = 128; st > 0; st >>= 1) {
        if (t < st) { redl[t] += redl[t + st]; redg[t] += redg[t + st]; }
        __syncthreads();
    }
    if (t == 0) { out[0] = redl[0]; out[1] = redg[0]; }
}

extern "C" void kernel_launch(void* const* d_in, const int* in_sizes, int n_in,
                              void* d_out, int out_size, void* d_ws, size_t ws_size,
                              hipStream_t stream) {
    const float* emb = (const float*)d_in[0];
    const float* gum = (const float*)d_in[1];
    const int*   Vi  = (const int*)d_in[2];
    const int*   Ei  = (const int*)d_in[3];
    float* out = (float*)d_out;

    char* ws = (char*)d_ws;
    size_t off = 0;
    pack_t* X = (pack_t*)(ws + off);    off += (size_t)V_NODES * 64 * sizeof(pack_t); // 6.4 MB
    pack_t* Y = (pack_t*)(ws + off);    off += (size_t)E_EDGES * 64 * sizeof(pack_t); // 3.2 MB
    unsigned short* listE = (unsigned short*)(ws + off); off += (size_t)NNZ * 2;      // 1.2 MB
    unsigned short* listV = (unsigned short*)(ws + off); off += (size_t)NNZ * 2;      // 1.2 MB
    int* cntE  = (int*)(ws + off);      off += (size_t)E_EDGES * 4;
    int* cntV  = (int*)(ws + off);      off += (size_t)V_NODES * 4;
    int* offE  = (int*)(ws + off);      off += (size_t)E_EDGES * 4;
    int* offV  = (int*)(ws + off);      off += (size_t)V_NODES * 4;
    int* curE  = (int*)(ws + off);      off += (size_t)E_EDGES * 4;
    int* curV  = (int*)(ws + off);      off += (size_t)V_NODES * 4;
    int* sums  = (int*)(ws + off);      off += (size_t)NTILES * 4;
    float* stats = (float*)(ws + off);  off += (size_t)8 * STATS_STRIDE * 4;
    float* partials = (float*)(ws + off);
    off += (size_t)8 * NBLK * STATS_STRIDE * 4;                            // 17.8 MB

    // zero counts (hist accumulates); everything else fully overwritten
    hipMemsetAsync(cntE, 0, ((size_t)E_EDGES + V_NODES) * 4, stream);

    softmax16_kernel<<<(V_NODES * 64 + 255) / 256, 256, 0, stream>>>(emb, gum, X);
    hist_kernel<<<(NNZ + 255) / 256, 256, 0, stream>>>(Vi, Ei, cntV, cntE);
    scanA_kernel<<<NTILES, 1024, 0, stream>>>(cntE, cntV, offE, offV, sums);
    scanB_kernel<<<1, 64, 0, stream>>>(sums);
    scanC_kernel<<<NTILES, 1024, 0, stream>>>(offE, offV, sums, curE, curV);
    fill_kernel<<<8 * FILL_BPG, 256, 0, stream>>>(Vi, Ei, curE, curV, listE, listV);

    const size_t PSIDE = (size_t)NBLK * STATS_STRIDE;
    for (int step = 0; step < NUM_STEP; ++step) {
        gather_stats<<<NBLK, 1024, 0, stream>>>(X, Y, listE, offE, cntE, E_EDGES,
                                                partials + (2*step) * PSIDE);
        gather_stats<<<NBLK, 1024, 0, stream>>>(Y, X, listV, offV, cntV, V_NODES,
                                                partials + (2*step + 1) * PSIDE);
    }

    reduce_all_kernel<<<(8 * STATS_STRIDE + 255) / 256, 256, 0, stream>>>(partials, stats);
    loss_kernel<<<1, 256, 0, stream>>>(stats, out);
}